// Round 9
// baseline (678.242 us; speedup 1.0000x reference)
//
#include <hip/hip_runtime.h>
#include <hip/hip_bf16.h>
#include <hip/hip_fp16.h>

#define NTOT 4194304
typedef __attribute__((ext_vector_type(4)))  short short4v;
typedef __attribute__((ext_vector_type(8)))  short short8v;
typedef __attribute__((ext_vector_type(4)))  float f32x4;

__device__ __forceinline__ ushort f2bf(float f){
    // hardware RNE cvt (compiler pairs into v_cvt_pk_bf16_f32)
    __hip_bfloat16 h = __float2bfloat16(f);
    return __bfloat16_as_ushort(h);
}
__device__ __forceinline__ float bf2f(ushort u){
    return __uint_as_float(((unsigned)u)<<16);
}

// ---------------- weight pack: per-lane MFMA B-fragment order, bf16 ----------------
// dwPk[l][ciq4][kkp5][koff2][cih2][jg2][co64][j4]
// owPk[l][ciq4][kkp5][koff2][cih2][jg2][co32][j4]
__global__ __launch_bounds__(256) void pack_w(
    const float* __restrict__ dw, const float* __restrict__ ow,
    ushort* __restrict__ dwPk, ushort* __restrict__ owPk,
    float* __restrict__ statsG)
{
    int i = blockIdx.x*256 + threadIdx.x;
    if (i < 286720) {
        int j = i&3, co = (i>>2)&63, jg=(i>>8)&1, cih=(i>>9)&1, koff=(i>>10)&1;
        int r = i>>11; int kkp = r%5; int r2 = r/5; int ciq = r2&3; int l = r2>>2;
        int kk = kkp*2+koff, ci = ciq*16 + cih*8 + jg*4 + j;
        float v = (kk<9)? dw[((l*64+co)*64+ci)*9+kk] : 0.f;
        dwPk[i] = f2bf(v);
    }
    if (i < 143360) {
        int j = i&3, co = (i>>2)&31, jg=(i>>7)&1, cih=(i>>8)&1, koff=(i>>9)&1;
        int r = i>>10; int kkp = r%5; int r2 = r/5; int ciq = r2&3; int l = r2>>2;
        int kk = kkp*2+koff, ci = ciq*16 + cih*8 + jg*4 + j;
        float v = (kk<9 && co<18)? ow[((l*18+co)*64+ci)*9+kk] : 0.f;
        owPk[i] = f2bf(v);
    }
    if (i < 7*1024) statsG[i] = 0.f;   // zero stats accumulators (capture-safe)
}

// kh/kw tables; index 9 clamps to kk=8 (ghost K-slots carry zero weights)
__constant__ int KHt[10] = {0,0,0,1,1,1,2,2,2,2};
__constant__ int KWt[10] = {0,1,2,0,1,2,0,1,2,2};

// ---------------- fused offset-conv + deformable conv ----------------
// Block: 256 thr = 4 waves; tile 2 rows x 32 cols; wave = 16 pixels (1 A-frag).
// Grid 1024, XCD-bijective decode. LDS 53504 B -> 3 blocks/CU = 12 waves/CU.
// xt: [spatial 10x40][ci 64] bf16, 16B slot XOR-swizzled by (spatial&7).
// A-frag lane: pixel = lane&15; k-slot: kk=2kkp+(lane>>5), ci=ciq*16+8*((lane>>4)&1)+j.
// C/D: col=lane&15 (co), row=(lane>>4)*4+reg (pix). Offsets in LDS as fp16.
__global__ __attribute__((amdgpu_flat_work_group_size(256,256), amdgpu_waves_per_eu(3,8)))
void dcn_layer(
    const float* __restrict__ xin, const ushort* __restrict__ owPk,
    const float* __restrict__ ob, const ushort* __restrict__ dwPk,
    float* __restrict__ y, float* __restrict__ statsL)
{
    __shared__ __align__(16) char smem[53504];
    ushort* offh = (ushort*)(smem + 51200);      // [64 pix][18] fp16 = 2304 B

    const int t = threadIdx.x, lane = t&63, w = t>>6;
    const int l15 = lane&15, lg = lane>>4;
    const int cih = lg&1, koff = lane>>5;
    const int bid = blockIdx.x;
    // XCD-aware bijective decode: xcd=bid&7 owns half an image (2MB < 4MB L2)
    const int xcd = bid&7, idx = bid>>3;
    const int b = xcd>>1, vh = xcd&1;
    const int ht = vh*32 + (idx>>2), wt = idx&3;
    const int w0 = wt*32, h0 = ht*2;
    const int wr = w>>1, wc = (w&1)*16;          // wave's row-in-tile, col-half
    const int row = h0 + wr;
    const int colbase = w0 + wc;
    const int RLO = h0-4, CLO = w0-4;            // 10 rows x 40 cols halo tile

    // ================= stage 64-ci halo tile (once) =================
#pragma unroll 1
    for (int i=0;i<25;i++){
        int d = i*256 + t;                 // 0..6399 : (cq 0..15) x (spatial 0..399)
        if (d < 6400) {
            int cq = d/400, sp = d - cq*400;
            int rowt = sp/40, colt = sp - rowt*40;
            int gy = RLO+rowt, gx = CLO+colt;
            bool ok = ((unsigned)gy<128u) && ((unsigned)gx<128u);
            const float* gp = xin + (((b<<6)+(cq<<2))<<14) + (gy<<7) + gx;
            short4v pk;
#pragma unroll
            for (int e=0;e<4;e++){
                float v = ok ? gp[e<<14] : 0.f;
                pk[e] = (short)f2bf(v);
            }
            int byt = sp*128 + (((cq>>1)^(sp&7))<<4) + ((cq&1)<<3);
            *(short4v*)(smem + byt) = pk;
        }
    }
    __syncthreads();

    // ================= pass 1: offset conv via MFMA (A from LDS) =================
    f32x4 oacc[2];
    oacc[0] = (f32x4){0.f,0.f,0.f,0.f};
    oacc[1] = (f32x4){0.f,0.f,0.f,0.f};

#pragma unroll 1
    for (int ciq=0; ciq<4; ++ciq) {
#pragma unroll 1
        for (int kkp=0; kkp<5; ++kkp) {
            int kkA = 2*kkp;
            int kkB = (kkA+1>8)?8:(kkA+1);
            int kh = koff ? KHt[kkB] : KHt[kkA];
            int kw = koff ? KWt[kkB] : KWt[kkA];
            int rowt = wr + kh + 3;                 // (row+kh-1)-RLO
            int colt = wc + l15 + kw + 3;           // (colbase+l15+kw-1)-CLO
            int sp = rowt*40 + colt;
            int byt = sp*128 + ((((ciq<<1)|cih) ^ (sp&7))<<4);
            short8v afr = *(const short8v*)(smem + byt);
            const ushort* wop = owPk + ciq*5120 + kkp*1024 + koff*512 + cih*256;
#pragma unroll
            for (int q=0;q<2;q++){
                short4v b0 = *(const short4v*)(wop +       (q*16+l15)*4);
                short4v b1 = *(const short4v*)(wop + 128 + (q*16+l15)*4);
                short8v bb = __builtin_shufflevector(b0,b1,0,1,2,3,4,5,6,7);
                oacc[q] = __builtin_amdgcn_mfma_f32_16x16x32_bf16(afr, bb, oacc[q], 0,0,0);
            }
        }
    }

    // redistribute offsets as fp16: offh[pix64][18]; only o<18
    {
        float biasq[2];
#pragma unroll
        for (int q=0;q<2;q++){ int o = q*16+l15; biasq[q] = (o<18)? ob[o] : 0.f; }
#pragma unroll
        for (int q=0;q<2;q++){
            int o = q*16+l15;
            if (o < 18) {
#pragma unroll
                for (int r=0;r<4;r++){
                    int pix = wr*32 + wc + lg*4 + r;
                    offh[pix*18 + o] = __half_as_ushort(__float2half(oacc[q][r] + biasq[q]));
                }
            }
        }
    }
    __syncthreads();

    // ================= pass 2: deformable conv via MFMA =================
    f32x4 acc[4];
#pragma unroll
    for (int q=0;q<4;q++) acc[q] = (f32x4){0.f,0.f,0.f,0.f};

#pragma unroll 1
    for (int kkp=0; kkp<5; ++kkp) {
        int kkA = 2*kkp;
        int kkB = (kkA+1>8)?8:(kkA+1);
        int kh = koff ? KHt[kkB] : KHt[kkA];
        int kw = koff ? KWt[kkB] : KWt[kkA];
        int kkX = koff ? kkB : kkA;

        // ---- hoisted (ciq-invariant): bilinear addresses + weights ----
        int pix = wr*32 + wc + l15;
        unsigned odp = *(const unsigned*)((const char*)offh + pix*36 + 4*kkX);
        float dy = __half2float(__ushort_as_half((ushort)(odp & 0xffffu)));
        float dx = __half2float(__ushort_as_half((ushort)(odp >> 16)));
        float py = (float)(row + kh - 1) + dy;
        float px = (float)(colbase + l15 + kw - 1) + dx;
        float fy = floorf(py), fx = floorf(px);
        float ly = py - fy, lx = px - fx;
        int y0 = (int)fy, x0 = (int)fx;
        int y1 = y0+1, x1 = x0+1;
        bool vy0 = ((unsigned)y0<128u), vy1 = ((unsigned)y1<128u);
        bool vx0 = ((unsigned)x0<128u), vx1 = ((unsigned)x1<128u);
        int y0c = min(max(y0,0),127), y1c = min(max(y1,0),127);
        int x0c = min(max(x0,0),127), x1c = min(max(x1,0),127);
        int r0 = y0c-RLO, r1 = y1c-RLO, c0 = x0c-CLO, c1 = x1c-CLO;
        bool ty0 = ((unsigned)r0<10u), ty1 = ((unsigned)r1<10u);
        bool tx0 = ((unsigned)c0<40u), tx1 = ((unsigned)c1<40u);
        float g00 = (vy0&&vx0) ? (1.f-ly)*(1.f-lx) : 0.f;
        float g01 = (vy0&&vx1) ? (1.f-ly)*lx       : 0.f;
        float g10 = (vy1&&vx0) ? ly*(1.f-lx)       : 0.f;
        float g11 = (vy1&&vx1) ? ly*lx             : 0.f;
        float f00 = (ty0&&tx0) ? g00 : 0.f;
        float f01 = (ty0&&tx1) ? g01 : 0.f;
        float f10 = (ty1&&tx0) ? g10 : 0.f;
        float f11 = (ty1&&tx1) ? g11 : 0.f;
        int rc0 = min(max(r0,0),9), rc1 = min(max(r1,0),9);
        int cc0 = min(max(c0,0),39), cc1 = min(max(c1,0),39);
        int s00 = rc0*40+cc0, s01 = rc0*40+cc1, s10 = rc1*40+cc0, s11 = rc1*40+cc1;
        // swizzled base; per-ciq address = base ^ (slot<<4)
        int b00 = (s00<<7) | ((s00&7)<<4);
        int b01 = (s01<<7) | ((s01&7)<<4);
        int b10 = (s10<<7) | ((s10&7)<<4);
        int b11 = (s11<<7) | ((s11&7)<<4);
        float rw00 = g00-f00, rw01 = g01-f01, rw10 = g10-f10, rw11 = g11-f11;
        bool anyfb = (rw00+rw01+rw10+rw11) > 0.f;
        int a00 = (y0c<<7)+x0c, a01 = (y0c<<7)+x1c;
        int a10 = (y1c<<7)+x0c, a11 = (y1c<<7)+x1c;

#pragma unroll 1
        for (int ciq=0; ciq<4; ++ciq) {
            int slotX = (((ciq<<1)|cih)<<4);
            short8v q00 = *(const short8v*)(smem + (b00 ^ slotX));
            short8v q01 = *(const short8v*)(smem + (b01 ^ slotX));
            short8v q10 = *(const short8v*)(smem + (b10 ^ slotX));
            short8v q11 = *(const short8v*)(smem + (b11 ^ slotX));
            float sv[8];
#pragma unroll
            for (int j=0;j<8;j++)
                sv[j] = f00*bf2f((ushort)q00[j]) + f01*bf2f((ushort)q01[j])
                      + f10*bf2f((ushort)q10[j]) + f11*bf2f((ushort)q11[j]);
            if (anyfb) {   // rare: in-image but out-of-tile corners, global fp32
                const float* xg = xin + (((b<<6) + ciq*16 + cih*8)<<14);
#pragma unroll
                for (int j=0;j<8;j++){
                    int o = j<<14;
                    sv[j] += rw00*xg[a00+o] + rw01*xg[a01+o]
                           + rw10*xg[a10+o] + rw11*xg[a11+o];
                }
            }
            short8v afr;
#pragma unroll
            for (int j=0;j<8;j++) afr[j] = (short)f2bf(sv[j]);
            const ushort* wp = dwPk + ciq*10240 + kkp*2048 + koff*1024 + cih*512;
#pragma unroll
            for (int q=0;q<4;q++){
                short4v b0 = *(const short4v*)(wp +       (q*16+l15)*4);
                short4v b1 = *(const short4v*)(wp + 256 + (q*16+l15)*4);
                short8v bb = __builtin_shufflevector(b0,b1,0,1,2,3,4,5,6,7);
                acc[q] = __builtin_amdgcn_mfma_f32_16x16x32_bf16(afr, bb, acc[q], 0,0,0);
            }
        }
    }

    // ================= epilogue: LDS transpose, store, stats =================
    float* yt  = (float*)smem;               // [32 co][68] f32 = 8704 B (overlays xt)
    float* red = (float*)(smem + 8704);      // 512 f32
#pragma unroll
    for (int half=0; half<2; ++half){
        __syncthreads();   // iter0: pass-2 xt reads done; iter1: prev stats reads done
#pragma unroll
        for (int qq=0;qq<2;qq++)
            *(f32x4*)(yt + (qq*16+l15)*68 + wr*32 + wc + lg*4) = acc[half*2+qq];
        __syncthreads();
#pragma unroll
        for (int i=0;i<2;i++){
            int f4 = i*256 + t;                       // 0..511
            int co = f4>>4, px4 = (f4&15)<<2;         // co<32, pix 0..63
            f32x4 v = *(const f32x4*)(yt + co*68 + px4);
            *(f32x4*)(y + (((b<<6) + half*32 + co)<<14)
                        + (h0 + (px4>>5))*128 + w0 + (px4&31)) = v;
        }
        {
            float s=0.f, s2=0.f;
            int co = t&31, seg = t>>5;                // 8 segs x 8 px
            const float* bp = yt + co*68 + seg*8;
#pragma unroll
            for (int qd=0;qd<8;qd++){ float v = bp[qd]; s += v; s2 += v*v; }
            red[seg*32+co] = s; red[256 + seg*32+co] = s2;
        }
        __syncthreads();
        if (t < 64){
            int vv = t>>5, cc = t&31;
            float a = 0.f;
#pragma unroll
            for (int g=0;g<8;g++) a += red[vv*256 + g*32 + cc];
            atomicAdd(statsL + (bid&7)*128 + vv*64 + half*32 + cc, a);
        }
    }
}

// ---------------- normalize + ReLU + epilogue, stats finalized inline ----------------
// mode 0: out = relu(.)   mode 1: out = relu(.) + addsrc   mode 2: out += relu(.)
__global__ __launch_bounds__(256) void norm2(
    const float* __restrict__ yv, const float* __restrict__ statsL,
    const float* __restrict__ gamma, const float* __restrict__ beta,
    const float* __restrict__ addsrc, float* out, int mode)
{
    const int i4 = blockIdx.x*256 + threadIdx.x;
    const int ch = (i4 >> 12) & 63;
    float sum=0.f, ssq=0.f;
#pragma unroll
    for (int s=0;s<8;s++){ sum += statsL[s*128+ch]; ssq += statsL[s*128+64+ch]; }
    float mean = sum*(1.f/65536.f);
    float var  = ssq*(1.f/65536.f) - mean*mean;
    float inv  = rsqrtf(var + 1e-5f);
    float sc = gamma[ch]*inv, sh = beta[ch] - mean*sc;
    float4 v = *(const float4*)&yv[i4*4];
    float4 rr;
    rr.x = fmaxf(v.x*sc+sh, 0.f);
    rr.y = fmaxf(v.y*sc+sh, 0.f);
    rr.z = fmaxf(v.z*sc+sh, 0.f);
    rr.w = fmaxf(v.w*sc+sh, 0.f);
    if (mode == 1) {
        float4 a = *(const float4*)&addsrc[i4*4];
        rr.x+=a.x; rr.y+=a.y; rr.z+=a.z; rr.w+=a.w;
    } else if (mode == 2) {
        float4 o = *(const float4*)&out[i4*4];
        rr.x+=o.x; rr.y+=o.y; rr.z+=o.z; rr.w+=o.w;
    }
    *(float4*)&out[i4*4] = rr;
}

// ---------------- host orchestration ----------------
extern "C" void kernel_launch(void* const* d_in, const int* in_sizes, int n_in,
                              void* d_out, int out_size, void* d_ws, size_t ws_size,
                              hipStream_t stream)
{
    const float* x  = (const float*)d_in[0];
    const float* ow = (const float*)d_in[1];
    const float* ob = (const float*)d_in[2];
    const float* dw = (const float*)d_in[3];
    const float* g  = (const float*)d_in[4];
    const float* be = (const float*)d_in[5];
    float* out = (float*)d_out;

    float*  yb     = (float*)d_ws;
    float*  P      = yb + NTOT;
    float*  Q      = P + NTOT;
    float*  statsG = Q + NTOT;               // 7*1024 f32
    ushort* dwPk   = (ushort*)(statsG + 7*1024);
    ushort* owPk   = dwPk + 286720;

    pack_w<<<1120, 256, 0, stream>>>(dw, ow, dwPk, owPk, statsG);

    auto L = [&](int l, const float* in, float* dst, int mode, const float* adds){
        dcn_layer<<<1024, 256, 0, stream>>>(in, owPk + l*20480, ob + l*18,
                                            dwPk + l*40960, yb, statsG + l*1024);
        norm2<<<4096, 256, 0, stream>>>(yb, statsG + l*1024, g + l*64, be + l*64,
                                        adds, dst, mode);
    };

    L(0, x, P,   0, nullptr);   // P = L0(x)
    L(1, P, P,   0, nullptr);   // P = L1(P)            (out_1)
    L(4, x, Q,   1, P);         // Q = L4(x) + P        (out_sum_1)
    L(2, Q, P,   0, nullptr);   // P = L2(Q)
    L(3, P, out, 0, nullptr);   // out = L3(P)
    L(5, Q, out, 2, nullptr);   // out += L5(Q)
    L(6, Q, out, 2, nullptr);   // out += L6(Q)
}

// Round 10
// 486.986 us; speedup vs baseline: 1.3927x; 1.3927x over previous
//
#include <hip/hip_runtime.h>
#include <hip/hip_bf16.h>

#define NTOT 4194304
typedef __attribute__((ext_vector_type(4)))  short short4v;
typedef __attribute__((ext_vector_type(8)))  short short8v;
typedef __attribute__((ext_vector_type(4)))  float f32x4;

__device__ __forceinline__ ushort f2bf(float f){
    __hip_bfloat16 h = __float2bfloat16(f);
    return __bfloat16_as_ushort(h);
}
__device__ __forceinline__ float bf2f(ushort u){
    return __uint_as_float(((unsigned)u)<<16);
}

// ---------------- weight pack: per-lane MFMA B-fragment order, bf16 ----------------
// dwPk[l][ciq4][kkp5][koff2][cih2][jg2][co64][j4]
// owPk[l][ciq4][kkp5][koff2][cih2][jg2][co32][j4]
__global__ __launch_bounds__(256) void pack_w(
    const float* __restrict__ dw, const float* __restrict__ ow,
    ushort* __restrict__ dwPk, ushort* __restrict__ owPk,
    float* __restrict__ statsG)
{
    int i = blockIdx.x*256 + threadIdx.x;
    if (i < 286720) {
        int j = i&3, co = (i>>2)&63, jg=(i>>8)&1, cih=(i>>9)&1, koff=(i>>10)&1;
        int r = i>>11; int kkp = r%5; int r2 = r/5; int ciq = r2&3; int l = r2>>2;
        int kk = kkp*2+koff, ci = ciq*16 + cih*8 + jg*4 + j;
        float v = (kk<9)? dw[((l*64+co)*64+ci)*9+kk] : 0.f;
        dwPk[i] = f2bf(v);
    }
    if (i < 143360) {
        int j = i&3, co = (i>>2)&31, jg=(i>>7)&1, cih=(i>>8)&1, koff=(i>>9)&1;
        int r = i>>10; int kkp = r%5; int r2 = r/5; int ciq = r2&3; int l = r2>>2;
        int kk = kkp*2+koff, ci = ciq*16 + cih*8 + jg*4 + j;
        float v = (kk<9 && co<18)? ow[((l*18+co)*64+ci)*9+kk] : 0.f;
        owPk[i] = f2bf(v);
    }
    if (i < 7*1024) statsG[i] = 0.f;   // zero stats accumulators (capture-safe)
}

// kh/kw tables; index 9 clamps to kk=8 (ghost K-slots carry zero weights)
__constant__ int KHt[10] = {0,0,0,1,1,1,2,2,2,2};
__constant__ int KWt[10] = {0,1,2,0,1,2,0,1,2,2};

// ---------------- fused offset-conv + deformable conv, single LDS stage ----------------
// Block: 512 thr = 8 waves; tile 8 rows x 32 cols; wave = 32 px (2 A-frags -> ILP).
// Grid 256, XCD-bijective decode. LDS 143360 B -> 1 block/CU (2 waves/EU).
// xt: [spatial 20x48][ci 64] bf16, 16B slot XOR-swizzled by (spatial&7).
// Slot XOR is ciq-linear: addr(ciq) = base ^ (ciq<<5)  (slot bits disjoint).
// A-frag lane: pixel = p*16+(lane&15); k-slot: kk=2kkp+(lane>>5), ci=ciq*16+8*((lane>>4)&1)+j.
// C/D: col=lane&15 (co), row=(lane>>4)*4+reg (pix).
// ciq loops FULLY UNROLLED: 16-32 independent ds_read_b128 in flight per kkp
// (round 9 lesson: unroll-1 left ds_read latency exposed at 2 waves/EU).
__global__ __attribute__((amdgpu_flat_work_group_size(512,512), amdgpu_waves_per_eu(2,2)))
void dcn_layer(
    const float* __restrict__ xin, const ushort* __restrict__ owPk,
    const float* __restrict__ ob, const ushort* __restrict__ dwPk,
    float* __restrict__ y, float* __restrict__ statsL)
{
    __shared__ __align__(16) char smem[143360];
    float* offl = (float*)(smem + 122880);       // [256][20] f32 = 20480 B

    const int t = threadIdx.x, lane = t&63, w = t>>6;
    const int l15 = lane&15, lg = lane>>4;
    const int cih = lg&1, koff = lane>>5;
    const int bid = blockIdx.x;
    // XCD-aware bijective decode: xcd=bid&7 owns half an image (1MB < 4MB L2)
    const int xcd = bid&7, idx = bid>>3;
    const int b = xcd>>1, vh = xcd&1;
    const int ht = vh*8 + (idx>>2), wt = idx&3;
    const int w0 = wt*32, h0 = ht*8;
    const int row = h0 + w;
    const int RLO = h0-6, CLO = w0-8;

    // ================= stage full 64-ci halo tile (once) =================
#pragma unroll 1
    for (int i=0;i<30;i++){
        int d = i*512 + t;                 // 0..15359 : (cq 0..15) x (spatial 0..959)
        int cq = d/960, spatial = d - cq*960;
        int rowt = spatial/48, colt = spatial - rowt*48;
        int gy = RLO+rowt, gx = CLO+colt;
        bool ok = ((unsigned)gy<128u) && ((unsigned)gx<128u);
        const float* gp = xin + (((b<<6)+(cq<<2))<<14) + (gy<<7) + gx;
        short4v pk;
#pragma unroll
        for (int e=0;e<4;e++){
            float v = ok ? gp[e<<14] : 0.f;
            pk[e] = (short)f2bf(v);
        }
        int byt = spatial*128 + (((cq>>1)^(spatial&7))<<4) + ((cq&1)<<3);
        *(short4v*)(smem + byt) = pk;
    }
    __syncthreads();

    // ================= pass 1: offset conv via MFMA (A from LDS) =================
    f32x4 oacc[2][2];
#pragma unroll
    for (int p=0;p<2;p++)
#pragma unroll
        for (int q=0;q<2;q++) oacc[p][q] = (f32x4){0.f,0.f,0.f,0.f};

#pragma unroll 1
    for (int kkp=0; kkp<5; ++kkp) {
        int kkA = 2*kkp;
        int kkB = (kkA+1>8)?8:(kkA+1);
        int kh = koff ? KHt[kkB] : KHt[kkA];
        int kw = koff ? KWt[kkB] : KWt[kkA];
        int bse[2];
#pragma unroll
        for (int p=0;p<2;p++){
            int sp = (w+5+kh)*48 + (p*16 + l15 + kw + 7);
            bse[p] = sp*128 + ((cih ^ (sp&7))<<4);
        }
#pragma unroll
        for (int ciq=0; ciq<4; ++ciq) {
            short8v afr[2];
            afr[0] = *(const short8v*)(smem + (bse[0] ^ (ciq<<5)));
            afr[1] = *(const short8v*)(smem + (bse[1] ^ (ciq<<5)));
            const ushort* wop = owPk + ciq*5120 + kkp*1024 + koff*512 + cih*256;
#pragma unroll
            for (int q=0;q<2;q++){
                short4v b0 = *(const short4v*)(wop +       (q*16+l15)*4);
                short4v b1 = *(const short4v*)(wop + 128 + (q*16+l15)*4);
                short8v bb = __builtin_shufflevector(b0,b1,0,1,2,3,4,5,6,7);
#pragma unroll
                for (int p=0;p<2;p++)
                    oacc[p][q] = __builtin_amdgcn_mfma_f32_16x16x32_bf16(afr[p], bb, oacc[p][q], 0,0,0);
            }
        }
    }

    // redistribute offsets: offl[pix 256][20]; only o<18 (stride-20 overflow guard)
    float biasq[2];
#pragma unroll
    for (int q=0;q<2;q++){ int o = q*16+l15; biasq[q] = (o<18)? ob[o] : 0.f; }
#pragma unroll
    for (int p=0;p<2;p++)
#pragma unroll
        for (int q=0;q<2;q++){
            int o = q*16+l15;
            if (o < 18) {
#pragma unroll
                for (int r=0;r<4;r++){
                    int pix = w*32 + p*16 + lg*4 + r;
                    offl[pix*20 + o] = oacc[p][q][r] + biasq[q];
                }
            }
        }
    __syncthreads();

    // ================= pass 2: deformable conv via MFMA =================
    f32x4 acc[2][4];
#pragma unroll
    for (int p=0;p<2;p++)
#pragma unroll
        for (int q=0;q<4;q++) acc[p][q] = (f32x4){0.f,0.f,0.f,0.f};

#pragma unroll 1
    for (int kkp=0; kkp<5; ++kkp) {
        int kkA = 2*kkp;
        int kkB = (kkA+1>8)?8:(kkA+1);
        int kh = koff ? KHt[kkB] : KHt[kkA];
        int kw = koff ? KWt[kkB] : KWt[kkA];
        int kkX = koff ? kkB : kkA;

        // ---- hoisted (ciq-invariant) bilinear per A-frag ----
        float f00a[2],f01a[2],f10a[2],f11a[2];
        float rw00a[2],rw01a[2],rw10a[2],rw11a[2];
        int b00a[2],b01a[2],b10a[2],b11a[2];
        int a00a[2],a01a[2],a10a[2],a11a[2];
        bool fba[2];
#pragma unroll
        for (int p=0;p<2;p++){
            int pix = w*32 + p*16 + l15;
            float2 od = *(const float2*)(offl + pix*20 + 2*kkX);
            float py = (float)(row + kh - 1) + od.x;
            float px = (float)(w0 + p*16 + l15 + kw - 1) + od.y;
            float fy = floorf(py), fx = floorf(px);
            float ly = py - fy, lx = px - fx;
            int y0 = (int)fy, x0 = (int)fx;
            int y1 = y0+1, x1 = x0+1;
            bool vy0 = ((unsigned)y0<128u), vy1 = ((unsigned)y1<128u);
            bool vx0 = ((unsigned)x0<128u), vx1 = ((unsigned)x1<128u);
            int y0c = min(max(y0,0),127), y1c = min(max(y1,0),127);
            int x0c = min(max(x0,0),127), x1c = min(max(x1,0),127);
            int r0 = y0c-RLO, r1 = y1c-RLO, c0 = x0c-CLO, c1 = x1c-CLO;
            bool ty0 = ((unsigned)r0<20u), ty1 = ((unsigned)r1<20u);
            bool tx0 = ((unsigned)c0<48u), tx1 = ((unsigned)c1<48u);
            float g00 = (vy0&&vx0) ? (1.f-ly)*(1.f-lx) : 0.f;
            float g01 = (vy0&&vx1) ? (1.f-ly)*lx       : 0.f;
            float g10 = (vy1&&vx0) ? ly*(1.f-lx)       : 0.f;
            float g11 = (vy1&&vx1) ? ly*lx             : 0.f;
            float f00 = (ty0&&tx0) ? g00 : 0.f;
            float f01 = (ty0&&tx1) ? g01 : 0.f;
            float f10 = (ty1&&tx0) ? g10 : 0.f;
            float f11 = (ty1&&tx1) ? g11 : 0.f;
            int rc0 = min(max(r0,0),19), rc1 = min(max(r1,0),19);
            int cc0 = min(max(c0,0),47), cc1 = min(max(c1,0),47);
            int s00 = rc0*48+cc0, s01 = rc0*48+cc1, s10 = rc1*48+cc0, s11 = rc1*48+cc1;
            f00a[p]=f00; f01a[p]=f01; f10a[p]=f10; f11a[p]=f11;
            rw00a[p]=g00-f00; rw01a[p]=g01-f01; rw10a[p]=g10-f10; rw11a[p]=g11-f11;
            b00a[p] = s00*128 + ((cih^(s00&7))<<4);
            b01a[p] = s01*128 + ((cih^(s01&7))<<4);
            b10a[p] = s10*128 + ((cih^(s10&7))<<4);
            b11a[p] = s11*128 + ((cih^(s11&7))<<4);
            fba[p] = (rw00a[p]+rw01a[p]+rw10a[p]+rw11a[p]) > 0.f;
            a00a[p]=(y0c<<7)+x0c; a01a[p]=(y0c<<7)+x1c;
            a10a[p]=(y1c<<7)+x0c; a11a[p]=(y1c<<7)+x1c;
        }

#pragma unroll
        for (int ciq=0; ciq<4; ++ciq) {
            short8v afr[2];
#pragma unroll
            for (int p=0;p<2;p++){
                short8v q00 = *(const short8v*)(smem + (b00a[p] ^ (ciq<<5)));
                short8v q01 = *(const short8v*)(smem + (b01a[p] ^ (ciq<<5)));
                short8v q10 = *(const short8v*)(smem + (b10a[p] ^ (ciq<<5)));
                short8v q11 = *(const short8v*)(smem + (b11a[p] ^ (ciq<<5)));
                float sv[8];
#pragma unroll
                for (int j=0;j<8;j++)
                    sv[j] = f00a[p]*bf2f((ushort)q00[j]) + f01a[p]*bf2f((ushort)q01[j])
                          + f10a[p]*bf2f((ushort)q10[j]) + f11a[p]*bf2f((ushort)q11[j]);
                if (fba[p]) {   // rare: in-image but out-of-tile corners, global fp32
                    const float* xg = xin + (((b<<6) + ciq*16 + cih*8)<<14);
#pragma unroll
                    for (int j=0;j<8;j++){
                        int o = j<<14;
                        sv[j] += rw00a[p]*xg[a00a[p]+o] + rw01a[p]*xg[a01a[p]+o]
                               + rw10a[p]*xg[a10a[p]+o] + rw11a[p]*xg[a11a[p]+o];
                    }
                }
#pragma unroll
                for (int j=0;j<8;j++) afr[p][j] = (short)f2bf(sv[j]);
            }
            const ushort* wp = dwPk + ciq*10240 + kkp*2048 + koff*1024 + cih*512;
#pragma unroll
            for (int q=0;q<4;q++){
                short4v b0 = *(const short4v*)(wp +       (q*16+l15)*4);
                short4v b1 = *(const short4v*)(wp + 256 + (q*16+l15)*4);
                short8v bb = __builtin_shufflevector(b0,b1,0,1,2,3,4,5,6,7);
                acc[0][q] = __builtin_amdgcn_mfma_f32_16x16x32_bf16(afr[0], bb, acc[0][q], 0,0,0);
                acc[1][q] = __builtin_amdgcn_mfma_f32_16x16x32_bf16(afr[1], bb, acc[1][q], 0,0,0);
            }
        }
    }

    // ================= epilogue: LDS transpose, store, stats (fully unrolled) =================
    float* yt  = (float*)smem;               // [32 co][260] = 33280 B (overlays xt)
    float* red = (float*)(smem + 33280);     // 1024 f32
#pragma unroll
    for (int half=0; half<2; ++half){
        __syncthreads();   // iter0: pass-2 xt reads done; iter1: prev stats reads done
#pragma unroll
        for (int p=0;p<2;p++)
#pragma unroll
            for (int qq=0;qq<2;qq++)
                *(f32x4*)(yt + (qq*16+l15)*260 + w*32 + p*16 + lg*4) = acc[p][half*2+qq];
        __syncthreads();
#pragma unroll
        for (int i=0;i<4;i++){
            int f4 = i*512 + t;
            int co = f4>>6, px4 = (f4&63)<<2;
            f32x4 v = *(const f32x4*)(yt + co*260 + px4);
            *(f32x4*)(y + (((b<<6) + half*32 + co)<<14) + (h0 + (px4>>5))*128 + w0 + (px4&31)) = v;
        }
        {
            float s=0.f, s2=0.f;
            int co = t&31, seg = t>>5;
            const float* bp = yt + co*260 + seg*16;
#pragma unroll
            for (int qd=0;qd<16;qd++){ float v = bp[qd]; s += v; s2 += v*v; }
            red[seg*32+co] = s; red[512 + seg*32+co] = s2;
        }
        __syncthreads();
        if (t < 64){
            int vv = t>>5, cc = t&31;
            float a = 0.f;
#pragma unroll
            for (int g=0;g<16;g++) a += red[vv*512 + g*32 + cc];
            atomicAdd(statsL + (bid&7)*128 + vv*64 + half*32 + cc, a);
        }
    }
}

// ---------------- normalize + ReLU + epilogue, stats finalized inline ----------------
// mode 0: out = relu(.)   mode 1: out = relu(.) + addsrc   mode 2: out += relu(.)
__global__ __launch_bounds__(256) void norm2(
    const float* __restrict__ yv, const float* __restrict__ statsL,
    const float* __restrict__ gamma, const float* __restrict__ beta,
    const float* __restrict__ addsrc, float* out, int mode)
{
    const int i4 = blockIdx.x*256 + threadIdx.x;
    const int ch = (i4 >> 12) & 63;
    float sum=0.f, ssq=0.f;
#pragma unroll
    for (int s=0;s<8;s++){ sum += statsL[s*128+ch]; ssq += statsL[s*128+64+ch]; }
    float mean = sum*(1.f/65536.f);
    float var  = ssq*(1.f/65536.f) - mean*mean;
    float inv  = rsqrtf(var + 1e-5f);
    float sc = gamma[ch]*inv, sh = beta[ch] - mean*sc;
    float4 v = *(const float4*)&yv[i4*4];
    float4 rr;
    rr.x = fmaxf(v.x*sc+sh, 0.f);
    rr.y = fmaxf(v.y*sc+sh, 0.f);
    rr.z = fmaxf(v.z*sc+sh, 0.f);
    rr.w = fmaxf(v.w*sc+sh, 0.f);
    if (mode == 1) {
        float4 a = *(const float4*)&addsrc[i4*4];
        rr.x+=a.x; rr.y+=a.y; rr.z+=a.z; rr.w+=a.w;
    } else if (mode == 2) {
        float4 o = *(const float4*)&out[i4*4];
        rr.x+=o.x; rr.y+=o.y; rr.z+=o.z; rr.w+=o.w;
    }
    *(float4*)&out[i4*4] = rr;
}

// ---------------- host orchestration ----------------
extern "C" void kernel_launch(void* const* d_in, const int* in_sizes, int n_in,
                              void* d_out, int out_size, void* d_ws, size_t ws_size,
                              hipStream_t stream)
{
    const float* x  = (const float*)d_in[0];
    const float* ow = (const float*)d_in[1];
    const float* ob = (const float*)d_in[2];
    const float* dw = (const float*)d_in[3];
    const float* g  = (const float*)d_in[4];
    const float* be = (const float*)d_in[5];
    float* out = (float*)d_out;

    float*  yb     = (float*)d_ws;
    float*  P      = yb + NTOT;
    float*  Q      = P + NTOT;
    float*  statsG = Q + NTOT;               // 7*1024 f32
    ushort* dwPk   = (ushort*)(statsG + 7*1024);
    ushort* owPk   = dwPk + 286720;

    pack_w<<<1120, 256, 0, stream>>>(dw, ow, dwPk, owPk, statsG);

    auto L = [&](int l, const float* in, float* dst, int mode, const float* adds){
        dcn_layer<<<256, 512, 0, stream>>>(in, owPk + l*20480, ob + l*18,
                                           dwPk + l*40960, yb, statsG + l*1024);
        norm2<<<4096, 256, 0, stream>>>(yb, statsG + l*1024, g + l*64, be + l*64,
                                        adds, dst, mode);
    };

    L(0, x, P,   0, nullptr);   // P = L0(x)
    L(1, P, P,   0, nullptr);   // P = L1(P)            (out_1)
    L(4, x, Q,   1, P);         // Q = L4(x) + P        (out_sum_1)
    L(2, Q, P,   0, nullptr);   // P = L2(Q)
    L(3, P, out, 0, nullptr);   // out = L3(P)
    L(5, Q, out, 2, nullptr);   // out += L5(Q)
    L(6, Q, out, 2, nullptr);   // out += L6(Q)
}